// Round 7
// baseline (368.605 us; speedup 1.0000x reference)
//
#include <hip/hip_runtime.h>
#include <hip/hip_bf16.h>

#define S_LEN   2048
#define BATCH   4
#define DMODEL  1024
#define NHEADS  16
#define HDIM    64
#define MROWS   (S_LEN * BATCH)

#define NE_ 8388608u
#define WE_ 1048576u

typedef unsigned int uint32;
typedef __attribute__((ext_vector_type(8))) short bf16x8;
typedef __attribute__((ext_vector_type(4))) float f32x4;

__device__ __forceinline__ ushort f2bf(float f) {
    uint32 u = __float_as_uint(f);
    uint32 r = (u + 0x7FFFu + ((u >> 16) & 1u)) >> 16;
    return (ushort)r;
}

__device__ __forceinline__ uint32 pk_bf16(float a, float b) {
    uint32 r;
    asm("v_cvt_pk_bf16_f32 %0, %1, %2" : "=v"(r) : "v"(a), "v"(b));
    return r;
}

__device__ __forceinline__ float exp2_asm(float x) {
    float r;
    asm("v_exp_f32 %0, %1" : "=v"(r) : "v"(x));
    return r;
}

__device__ __forceinline__ void gl16(const ushort* g, ushort* l) {
    __builtin_amdgcn_global_load_lds(
        (const __attribute__((address_space(1))) unsigned int*)g,
        (__attribute__((address_space(3))) unsigned int*)l,
        16, 0, 0);
}

// ---------------------------------------------------------------------------
// fp32 -> bf16 one-shot conversion (q,k,v + 4 weights) into ws.
// ---------------------------------------------------------------------------
__global__ __launch_bounds__(256) void cvt_all(const float* __restrict__ q,
                                               const float* __restrict__ k,
                                               const float* __restrict__ v,
                                               const float* __restrict__ wq,
                                               const float* __restrict__ wk,
                                               const float* __restrict__ wv,
                                               const float* __restrict__ wo,
                                               ushort* __restrict__ ws) {
    int i = blockIdx.x * 256 + threadIdx.x;
    const float* src;
    ushort* dst;
    int j;
    if (i < 3 * 2097152) {
        int t = i >> 21;
        j = i & 2097151;
        src = (t == 0) ? q : (t == 1) ? k : v;
        dst = ws + (size_t)t * NE_;
    } else {
        int u2 = i - 3 * 2097152;
        int t = u2 >> 18;
        j = u2 & 262143;
        src = (t == 0) ? wq : (t == 1) ? wk : (t == 2) ? wv : wo;
        dst = ws + 3 * (size_t)NE_ + (size_t)t * WE_;
    }
    float4 f = ((const float4*)src)[j];
    ushort4 u;
    u.x = f2bf(f.x); u.y = f2bf(f.y); u.z = f2bf(f.z); u.w = f2bf(f.w);
    ((ushort4*)dst)[j] = u;
}

// ---------------------------------------------------------------------------
// ROUND-7: unified projection GEMM with T3-minimum double-buffered K-loop.
// Per iter: STAGE(buf^1, next k) issued FIRST, then ds_read+MFMA on buf,
// then ONE __syncthreads (drains vmcnt+lgkmcnt; guards buffer handoff).
// 16 barrier-epochs per block instead of 64; gl16 latency hides under the
// 16-MFMA compute phase. (Guide m248v2: this exact recipe = 1.10x on GEMM;
// identical structure gave 1.10x on attn here in round 3.)
// Modes (arg, not gridDim hack):
//  0: merged grid 1536. Panel-clustered swizzle: p = bid%24 (pid=p>>3,
//     n_idx=p&7), m_idx = bid/24. bid%8 == p%8 -> the 64 blocks sharing a
//     B-panel land on one XCD (T1 regime: shared operand panel).
//  1: grid 1024, pid = bid>>9 (Q,K) — fallback when ws too small for a
//     non-aliased Vt.
//  2: grid 512, pid = 2 (V) — fallback.
// Epilogues: round-5 direct stores (round-6 LDS restage measured -9 us net).
// ---------------------------------------------------------------------------
__global__ __launch_bounds__(256) void proj_gemm(const ushort* __restrict__ abase,
                                                 const ushort* __restrict__ wbase,
                                                 const float* __restrict__ FC,
                                                 ushort* __restrict__ Qh,
                                                 ushort* __restrict__ Kh,
                                                 ushort* __restrict__ Vt,
                                                 int mode) {
    __shared__ __align__(16) ushort SM[16384];   // 2 bufs x (A 4096 | B 4096)

    const int tid  = threadIdx.x;
    const int lane = tid & 63;
    const int wvx  = tid >> 6;
    const int wm   = wvx >> 1, wn = wvx & 1;
    const int quad = lane >> 4, l16 = lane & 15;

    int pid, m_idx, n_idx;
    if (mode == 0) {
        int p = blockIdx.x % 24;
        m_idx = blockIdx.x / 24;
        pid   = p >> 3;
        n_idx = p & 7;
    } else if (mode == 1) {
        pid   = blockIdx.x >> 9;
        int local = blockIdx.x & 511;
        m_idx = local >> 3;
        n_idx = local & 7;
    } else {
        pid   = 2;
        m_idx = blockIdx.x >> 3;
        n_idx = blockIdx.x & 7;
    }
    const int m0 = m_idx * 128;
    const int n0 = n_idx * 128;

    const ushort* A = abase + (size_t)pid * NE_;
    const ushort* W = wbase + (size_t)pid * WE_;

    const int srow = tid >> 2;
    const int scol = (tid & 3) * 8;

    f32x4 acc[4][4] = {};

    // prologue: stage k-tile 0 into buf 0
    {
        ushort* D = &SM[0];
        gl16(&A[(size_t)(m0 + srow) * 1024 + scol],        D + tid * 8);
        gl16(&A[(size_t)(m0 + 64 + srow) * 1024 + scol],   D + 2048 + tid * 8);
        gl16(&W[(size_t)(n0 + srow) * 1024 + scol],        D + 4096 + tid * 8);
        gl16(&W[(size_t)(n0 + 64 + srow) * 1024 + scol],   D + 6144 + tid * 8);
    }
    __syncthreads();

#pragma unroll 2
    for (int kt = 0; kt < 32; ++kt) {
        const int cur = kt & 1;
        if (kt < 31) {                     // stage next tile BEFORE compute
            const int kk = (kt + 1) * 32;
            ushort* D = &SM[(cur ^ 1) * 8192];
            gl16(&A[(size_t)(m0 + srow) * 1024 + kk + scol],      D + tid * 8);
            gl16(&A[(size_t)(m0 + 64 + srow) * 1024 + kk + scol], D + 2048 + tid * 8);
            gl16(&W[(size_t)(n0 + srow) * 1024 + kk + scol],      D + 4096 + tid * 8);
            gl16(&W[(size_t)(n0 + 64 + srow) * 1024 + kk + scol], D + 6144 + tid * 8);
        }

        const ushort* Ab = &SM[cur * 8192 + (wm * 64 + l16) * 32 + quad * 8];
        const ushort* Bb = &SM[cur * 8192 + 4096 + (wn * 64 + l16) * 32 + quad * 8];
        bf16x8 af[4], bfr[4];
#pragma unroll
        for (int i = 0; i < 4; ++i) af[i]  = *(const bf16x8*)(Ab + i * 512);
#pragma unroll
        for (int i = 0; i < 4; ++i) bfr[i] = *(const bf16x8*)(Bb + i * 512);
#pragma unroll
        for (int im = 0; im < 4; ++im)
#pragma unroll
            for (int in = 0; in < 4; ++in)
                acc[im][in] = __builtin_amdgcn_mfma_f32_16x16x32_bf16(
                    af[im], bfr[in], acc[im][in], 0, 0, 0);

        __syncthreads();   // drains next-tile gl16 + buffer-reuse guard
    }

    if (pid < 2) {
        // ---- Q/K epilogue: RoPE + direct stores (round-5 form) ----
        ushort* outb    = pid ? Kh : Qh;
        const float osc = pid ? 1.0f : 0.18033688011111793f;
#pragma unroll
        for (int im = 0; im < 4; ++im) {
            int mbase = m0 + wm * 64 + im * 16 + quad * 4;
            int s = mbase >> 2;
#pragma unroll
            for (int in = 0; in < 4; ++in) {
                int e = n0 + wn * 64 + in * 16 + l16;
                int h = e >> 6, dd = e & 63;
                float2 cs = *(const float2*)&FC[s * 64 + (dd & ~1)];
                float sgn = (dd & 1) ? 1.0f : -1.0f;
#pragma unroll
                for (int rr = 0; rr < 4; ++rr) {
                    float vv = acc[im][in][rr];
                    float pp = __shfl_xor(vv, 1, 64);
                    float ov = (vv * cs.x + sgn * pp * cs.y) * osc;
                    outb[((size_t)(rr * NHEADS + h) * S_LEN + s) * HDIM + dd] = f2bf(ov);
                }
            }
        }
    } else {
        // ---- V epilogue: sigma-permuted transpose, direct stores ----
#pragma unroll
        for (int im = 0; im < 4; ++im) {
            int mbase = m0 + wm * 64 + im * 16 + quad * 4;
            int s = mbase >> 2;
            int nt2 = (s >> 4) & 3;
            int qd  = (s >> 2) & 3;
            int r2  = s & 3;
            int pos = (s & ~63) | ((nt2 >> 1) << 5) | (qd << 3) | ((nt2 & 1) << 2) | r2;
#pragma unroll
            for (int in = 0; in < 4; ++in) {
                int e = n0 + wn * 64 + in * 16 + l16;
                int h = e >> 6, dd = e & 63;
#pragma unroll
                for (int rr = 0; rr < 4; ++rr) {
                    Vt[((size_t)(rr * NHEADS + h) * HDIM + dd) * S_LEN + pos] =
                        f2bf(acc[im][in][rr]);
                }
            }
        }
    }
}

// ---------------------------------------------------------------------------
// Output projection with the same T3-minimum dbuf K-loop. fp32 row stores.
// ---------------------------------------------------------------------------
__global__ __launch_bounds__(256) void out_gemm(const ushort* __restrict__ A,
                                                const ushort* __restrict__ W,
                                                float* __restrict__ outf) {
    __shared__ __align__(16) ushort SM[16384];

    const int tid  = threadIdx.x;
    const int lane = tid & 63;
    const int wvx  = tid >> 6;
    const int wm   = wvx >> 1, wn = wvx & 1;
    const int quad = lane >> 4, l16 = lane & 15;
    const int m0 = (blockIdx.x >> 3) * 128;
    const int n0 = (blockIdx.x & 7) * 128;

    const int srow = tid >> 2;
    const int scol = (tid & 3) * 8;

    f32x4 acc[4][4] = {};

    {
        ushort* D = &SM[0];
        gl16(&A[(size_t)(m0 + srow) * 1024 + scol],        D + tid * 8);
        gl16(&A[(size_t)(m0 + 64 + srow) * 1024 + scol],   D + 2048 + tid * 8);
        gl16(&W[(size_t)(n0 + srow) * 1024 + scol],        D + 4096 + tid * 8);
        gl16(&W[(size_t)(n0 + 64 + srow) * 1024 + scol],   D + 6144 + tid * 8);
    }
    __syncthreads();

#pragma unroll 2
    for (int kt = 0; kt < 32; ++kt) {
        const int cur = kt & 1;
        if (kt < 31) {
            const int kk = (kt + 1) * 32;
            ushort* D = &SM[(cur ^ 1) * 8192];
            gl16(&A[(size_t)(m0 + srow) * 1024 + kk + scol],      D + tid * 8);
            gl16(&A[(size_t)(m0 + 64 + srow) * 1024 + kk + scol], D + 2048 + tid * 8);
            gl16(&W[(size_t)(n0 + srow) * 1024 + kk + scol],      D + 4096 + tid * 8);
            gl16(&W[(size_t)(n0 + 64 + srow) * 1024 + kk + scol], D + 6144 + tid * 8);
        }

        const ushort* Ab = &SM[cur * 8192 + (wm * 64 + l16) * 32 + quad * 8];
        const ushort* Bb = &SM[cur * 8192 + 4096 + (wn * 64 + l16) * 32 + quad * 8];
        bf16x8 af[4], bfr[4];
#pragma unroll
        for (int i = 0; i < 4; ++i) af[i]  = *(const bf16x8*)(Ab + i * 512);
#pragma unroll
        for (int i = 0; i < 4; ++i) bfr[i] = *(const bf16x8*)(Bb + i * 512);
#pragma unroll
        for (int im = 0; im < 4; ++im)
#pragma unroll
            for (int in = 0; in < 4; ++in)
                acc[im][in] = __builtin_amdgcn_mfma_f32_16x16x32_bf16(
                    af[im], bfr[in], acc[im][in], 0, 0, 0);

        __syncthreads();
    }

#pragma unroll
    for (int im = 0; im < 4; ++im) {
        int mbase = m0 + wm * 64 + im * 16 + quad * 4;
#pragma unroll
        for (int in = 0; in < 4; ++in) {
            int e = n0 + wn * 64 + in * 16 + l16;
#pragma unroll
            for (int rr = 0; rr < 4; ++rr)
                outf[(size_t)(mbase + rr) * 1024 + e] = acc[im][in][rr];
        }
    }
}

// ---------------------------------------------------------------------------
// MFMA flash attention — unchanged (at the plain-HIP structure ceiling,
// ~828 TF). Counted-vmcnt dbuf pipeline, in-register softmax via swapped
// operands, sigma-permuted PV, XCD head clustering.
// ---------------------------------------------------------------------------
__global__ __launch_bounds__(256, 4) void attn_mfma(const ushort* __restrict__ Qb,
                                                    const ushort* __restrict__ Kb,
                                                    const ushort* __restrict__ Vt,
                                                    ushort* __restrict__ Ob) {
    __shared__ __align__(16) ushort KV[16384];

    const int tid  = threadIdx.x;
    const int lane = tid & 63;
    const int wv   = tid >> 6;
    const int quad = lane >> 4;
    const int l16  = lane & 15;

    const int bid  = blockIdx.x;
    const int xcd  = bid & 7;
    const int slot = bid >> 3;
    const int head = ((slot >> 4) << 3) | xcd;
    const int qt   = slot & 15;

    const int q0   = qt * 128 + wv * 32;
    const size_t hb = (size_t)head * (S_LEN * HDIM);

    bf16x8 qf[2][2];
#pragma unroll
    for (int im = 0; im < 2; ++im)
#pragma unroll
        for (int kk = 0; kk < 2; ++kk)
            qf[im][kk] = *(const bf16x8*)
                &Qb[hb + (size_t)(q0 + im * 16 + l16) * HDIM + kk * 32 + quad * 8];

    f32x4 o[2][4] = {};
    float lsum[2] = {0.f, 0.f};

    const int srow = tid >> 3;
    const int scol = (((tid & 7) ^ (srow & 7)) * 8);
    const int sx   = (l16 & 7) * 8;

    {
        ushort* dst = &KV[0];
        gl16(&Kb[hb + (size_t)(srow) * HDIM + scol],        dst + tid * 8);
        gl16(&Kb[hb + (size_t)(32 + srow) * HDIM + scol],   dst + 2048 + tid * 8);
        gl16(&Vt[hb + (size_t)srow * S_LEN + scol],         dst + 4096 + tid * 8);
        gl16(&Vt[hb + (size_t)(32 + srow) * S_LEN + scol],  dst + 4096 + 2048 + tid * 8);
    }

#pragma unroll 2
    for (int t = 0; t < 32; ++t) {
        if (t < 31) {
            ushort* dst = &KV[((t + 1) & 1) * 8192];
            const int kc = (t + 1) * 64;
            gl16(&Kb[hb + (size_t)(kc + srow) * HDIM + scol],      dst + tid * 8);
            gl16(&Kb[hb + (size_t)(kc + 32 + srow) * HDIM + scol], dst + 2048 + tid * 8);
            gl16(&Vt[hb + (size_t)srow * S_LEN + kc + scol],       dst + 4096 + tid * 8);
            gl16(&Vt[hb + (size_t)(32 + srow) * S_LEN + kc + scol], dst + 4096 + 2048 + tid * 8);
            asm volatile("s_waitcnt vmcnt(4)" ::: "memory");
        } else {
            asm volatile("s_waitcnt vmcnt(0)" ::: "memory");
        }
        __builtin_amdgcn_s_barrier();
        __builtin_amdgcn_sched_barrier(0);

        const ushort* Ksub = &KV[(t & 1) * 8192];
        const ushort* Vsub = Ksub + 4096;

        f32x4 st[2][4] = {};
        __builtin_amdgcn_s_setprio(1);
#pragma unroll
        for (int nt = 0; nt < 4; ++nt) {
            bf16x8 kf0 = *(const bf16x8*)&Ksub[(nt * 16 + l16) * 64 + ((quad * 8) ^ sx)];
            bf16x8 kf1 = *(const bf16x8*)&Ksub[(nt * 16 + l16) * 64 + ((32 + quad * 8) ^ sx)];
#pragma unroll
            for (int im = 0; im < 2; ++im) {
                st[im][nt] = __builtin_amdgcn_mfma_f32_16x16x32_bf16(
                    kf0, qf[im][0], st[im][nt], 0, 0, 0);
                st[im][nt] = __builtin_amdgcn_mfma_f32_16x16x32_bf16(
                    kf1, qf[im][1], st[im][nt], 0, 0, 0);
            }
        }
        __builtin_amdgcn_s_setprio(0);

        union { uint32 d[16]; bf16x8 v[4]; } P;
#pragma unroll
        for (int im = 0; im < 2; ++im) {
            float ls = 0.f;
#pragma unroll
            for (int nt = 0; nt < 4; ++nt) {
                float p0 = exp2_asm(st[im][nt][0]);
                float p1 = exp2_asm(st[im][nt][1]);
                float p2 = exp2_asm(st[im][nt][2]);
                float p3 = exp2_asm(st[im][nt][3]);
                ls += (p0 + p1) + (p2 + p3);
                P.d[im * 8 + nt * 2]     = pk_bf16(p0, p1);
                P.d[im * 8 + nt * 2 + 1] = pk_bf16(p2, p3);
            }
            lsum[im] += ls;
        }

        __builtin_amdgcn_s_setprio(1);
#pragma unroll
        for (int dt = 0; dt < 4; ++dt) {
            bf16x8 vf0 = *(const bf16x8*)&Vsub[(dt * 16 + l16) * 64 + ((quad * 8) ^ sx)];
            bf16x8 vf1 = *(const bf16x8*)&Vsub[(dt * 16 + l16) * 64 + ((32 + quad * 8) ^ sx)];
#pragma unroll
            for (int im = 0; im < 2; ++im) {
                o[im][dt] = __builtin_amdgcn_mfma_f32_16x16x32_bf16(
                    vf0, P.v[im * 2], o[im][dt], 0, 0, 0);
                o[im][dt] = __builtin_amdgcn_mfma_f32_16x16x32_bf16(
                    vf1, P.v[im * 2 + 1], o[im][dt], 0, 0, 0);
            }
        }
        __builtin_amdgcn_s_setprio(0);

        __builtin_amdgcn_s_barrier();
        __builtin_amdgcn_sched_barrier(0);
    }

#pragma unroll
    for (int im = 0; im < 2; ++im) {
        lsum[im] += __shfl_xor(lsum[im], 16, 64);
        lsum[im] += __shfl_xor(lsum[im], 32, 64);
    }

    ushort* Est = &KV[wv * 2048];
#pragma unroll
    for (int im = 0; im < 2; ++im) {
        float inv = 1.0f / lsum[im];
#pragma unroll
        for (int dt = 0; dt < 4; ++dt) {
            uint2 w;
            w.x = pk_bf16(o[im][dt][0] * inv, o[im][dt][1] * inv);
            w.y = pk_bf16(o[im][dt][2] * inv, o[im][dt][3] * inv);
            *(uint2*)&Est[(im * 16 + l16) * 64 + dt * 16 + quad * 4] = w;
        }
    }
    __syncthreads();

    const int row  = lane >> 1, half = lane & 1;
    const int b = head >> 4, h = head & 15;
    const size_t ob = (size_t)((q0 + row) * BATCH + b) * 1024 + h * 64 + half * 32;
#pragma unroll
    for (int e = 0; e < 4; ++e) {
        bf16x8 t = *(const bf16x8*)&Est[row * 64 + half * 32 + e * 8];
        *(bf16x8*)&Ob[ob + e * 8] = t;
    }
}

extern "C" void kernel_launch(void* const* d_in, const int* in_sizes, int n_in,
                              void* d_out, int out_size, void* d_ws, size_t ws_size,
                              hipStream_t stream) {
    const float* q   = (const float*)d_in[0];
    const float* k   = (const float*)d_in[1];
    const float* v   = (const float*)d_in[2];
    const float* fc  = (const float*)d_in[3];
    const float* wq  = (const float*)d_in[4];
    const float* wk  = (const float*)d_in[5];
    const float* wvp = (const float*)d_in[6];
    const float* wo  = (const float*)d_in[7];

    ushort* ws = (ushort*)d_ws;
    // ws base layout (56 MB): qb | kb | vb | wqb wkb wvb wob
    ushort* qb  = ws;
    ushort* kb  = ws + NE_;
    ushort* wqb = ws + 3 * (size_t)NE_;
    ushort* wob = wqb + 3 * (size_t)WE_;

    ushort* Qh = (ushort*)d_out;
    ushort* Kh = Qh + NE_;
    ushort* R3 = ws + NE_;      // kb region (dead after proj)

    // Merged single-launch proj needs a Vt region disjoint from qb/kb/vb
    // (all three are read concurrently inside one launch). Use the tail of
    // ws if it is large enough; otherwise fall back to the two-launch split
    // (Vt aliases qb, which is safe across launch boundaries).
    const size_t baseElems = 3 * (size_t)NE_ + 4 * (size_t)WE_;   // 56 MB
    const bool   bigWs     = ws_size >= (baseElems + NE_) * sizeof(ushort);
    ushort* Vt = bigWs ? (ws + baseElems) : qb;

    // 1. convert everything to bf16
    cvt_all<<<28672, 256, 0, stream>>>(q, k, v, wq, wk, wvp, wo, ws);

    // 2. projections (dbuf K-loop)
    if (bigWs) {
        proj_gemm<<<1536, 256, 0, stream>>>(ws, wqb, fc, Qh, Kh, Vt, 0);
    } else {
        proj_gemm<<<1024, 256, 0, stream>>>(ws, wqb, fc, Qh, Kh, Vt, 1);
        proj_gemm<<<512, 256, 0, stream>>>(ws, wqb, fc, Qh, Kh, Vt, 2);
    }

    // 3. attention -> kb region
    attn_mfma<<<1024, 256, 0, stream>>>(Qh, Kh, Vt, R3);

    // 4. output projection (dbuf K-loop) -> d_out fp32
    out_gemm<<<512, 256, 0, stream>>>(R3, wob, (float*)d_out);
}

// Round 8
// 346.430 us; speedup vs baseline: 1.0640x; 1.0640x over previous
//
#include <hip/hip_runtime.h>
#include <hip/hip_bf16.h>

// Problem constants
#define S_LEN   2048
#define BATCH   4
#define DMODEL  1024
#define NHEADS  16
#define HDIM    64
#define MROWS   (S_LEN * BATCH)   // 8192

#define NE_ 8388608u   // elements per 8192x1024 bf16 buffer (16 MB)
#define WE_ 1048576u   // elements per 1024x1024 bf16 weight  (2 MB)

typedef unsigned int uint32;
typedef __attribute__((ext_vector_type(8))) short bf16x8;
typedef __attribute__((ext_vector_type(4))) float f32x4;

__device__ __forceinline__ ushort f2bf(float f) {
    uint32 u = __float_as_uint(f);
    uint32 r = (u + 0x7FFFu + ((u >> 16) & 1u)) >> 16;
    return (ushort)r;
}

// v_cvt_pk_bf16_f32: lo16 = bf16(a), hi16 = bf16(b)  (no builtin on gfx950)
__device__ __forceinline__ uint32 pk_bf16(float a, float b) {
    uint32 r;
    asm("v_cvt_pk_bf16_f32 %0, %1, %2" : "=v"(r) : "v"(a), "v"(b));
    return r;
}

// raw v_exp_f32: computes 2^x
__device__ __forceinline__ float exp2_asm(float x) {
    float r;
    asm("v_exp_f32 %0, %1" : "=v"(r) : "v"(x));
    return r;
}

// async global->LDS, 16B per lane (dest must be wave-uniform base + lane*16)
__device__ __forceinline__ void gl16(const ushort* g, ushort* l) {
    __builtin_amdgcn_global_load_lds(
        (const __attribute__((address_space(1))) unsigned int*)g,
        (__attribute__((address_space(3))) unsigned int*)l,
        16, 0, 0);
}

// ---------------------------------------------------------------------------
// fp32 -> bf16 one-shot conversion (q,k,v + 4 weights) into ws.
// ---------------------------------------------------------------------------
__global__ __launch_bounds__(256) void cvt_all(const float* __restrict__ q,
                                               const float* __restrict__ k,
                                               const float* __restrict__ v,
                                               const float* __restrict__ wq,
                                               const float* __restrict__ wk,
                                               const float* __restrict__ wv,
                                               const float* __restrict__ wo,
                                               ushort* __restrict__ ws) {
    int i = blockIdx.x * 256 + threadIdx.x;
    const float* src;
    ushort* dst;
    int j;
    if (i < 3 * 2097152) {
        int t = i >> 21;
        j = i & 2097151;
        src = (t == 0) ? q : (t == 1) ? k : v;
        dst = ws + (size_t)t * NE_;
    } else {
        int u2 = i - 3 * 2097152;
        int t = u2 >> 18;
        j = u2 & 262143;
        src = (t == 0) ? wq : (t == 1) ? wk : (t == 2) ? wv : wo;
        dst = ws + 3 * (size_t)NE_ + (size_t)t * WE_;
    }
    float4 f = ((const float4*)src)[j];
    ushort4 u;
    u.x = f2bf(f.x); u.y = f2bf(f.y); u.z = f2bf(f.z); u.w = f2bf(f.w);
    ((ushort4*)dst)[j] = u;
}

// ---------------------------------------------------------------------------
// Fused Q+K projection GEMM + RoPE epilogue (round-5 structure: 2-phase
// gl16 K-loop, direct stores — rounds 6/7's restage/dbuf/merge all measured
// neutral-to-negative and are reverted).
// ROUND-8 CHANGE (the only one): (m,n) decode transposed —
//   m_idx = local & 63, n_idx = local >> 6   (was m=local>>3, n=local&7).
// The 8 blocks sharing an A-panel (same m, n=0..7) now have bids congruent
// mod 8 -> land on ONE XCD -> A-panel (256 KB) fetched once per XCD instead
// of 8x (round-7 PMC: 211 MB FETCH vs 54 MB compulsory). B-panels (2 MB
// total) become the 8x-fetched operand — 14 MB extra vs ~320 MB saved.
// Q output pre-scaled by 1/sqrt(hd)*log2(e) for the attn kernel's v_exp_f32.
// ---------------------------------------------------------------------------
__global__ __launch_bounds__(256) void qk_gemm(const ushort* __restrict__ qb,
                                               const ushort* __restrict__ kb,
                                               const ushort* __restrict__ wqb,
                                               const ushort* __restrict__ wkb,
                                               const float* __restrict__ FC,
                                               ushort* __restrict__ Qh,
                                               ushort* __restrict__ Kh) {
    __shared__ __align__(16) ushort A_lds[128 * 32];
    __shared__ __align__(16) ushort B_lds[128 * 32];

    const int tid  = threadIdx.x;
    const int lane = tid & 63;
    const int wvx  = tid >> 6;
    const int wm   = wvx >> 1, wn = wvx & 1;
    const int quad = lane >> 4, l16 = lane & 15;
    const int pid   = blockIdx.x >> 9;       // 0:Q 1:K
    const int local = blockIdx.x & 511;
    const int m0 = (local & 63) * 128;       // A-panel-clustered (see header)
    const int n0 = (local >> 6) * 128;

    const ushort* A = pid ? kb : qb;
    const ushort* W = pid ? wkb : wqb;
    ushort* outb    = pid ? Kh : Qh;
    const float osc = pid ? 1.0f : 0.18033688011111793f;

    const int srow = tid >> 2;        // 0..63
    const int scol = (tid & 3) * 8;   // 0,8,16,24

    f32x4 acc[4][4] = {};

    for (int k0 = 0; k0 < 1024; k0 += 32) {
        __syncthreads();
        gl16(&A[(size_t)(m0 + srow) * 1024 + k0 + scol],      &A_lds[tid * 8]);
        gl16(&A[(size_t)(m0 + 64 + srow) * 1024 + k0 + scol], &A_lds[2048 + tid * 8]);
        gl16(&W[(size_t)(n0 + srow) * 1024 + k0 + scol],      &B_lds[tid * 8]);
        gl16(&W[(size_t)(n0 + 64 + srow) * 1024 + k0 + scol], &B_lds[2048 + tid * 8]);
        __syncthreads();

        const ushort* Ab = &A_lds[(wm * 64 + l16) * 32 + quad * 8];
        const ushort* Bb = &B_lds[(wn * 64 + l16) * 32 + quad * 8];
        bf16x8 af[4], bfr[4];
#pragma unroll
        for (int i = 0; i < 4; ++i) af[i]  = *(const bf16x8*)(Ab + i * 512);
#pragma unroll
        for (int i = 0; i < 4; ++i) bfr[i] = *(const bf16x8*)(Bb + i * 512);
#pragma unroll
        for (int im = 0; im < 4; ++im)
#pragma unroll
            for (int in = 0; in < 4; ++in)
                acc[im][in] = __builtin_amdgcn_mfma_f32_16x16x32_bf16(
                    af[im], bfr[in], acc[im][in], 0, 0, 0);
    }

    // Epilogue. C/D layout: col=l16, row=quad*4+rr. m = mbase+rr, mbase%4==0
    // => s = mbase>>2 wave-uniform, b = rr. RoPE pair partner = lane l16^1.
#pragma unroll
    for (int im = 0; im < 4; ++im) {
        int mbase = m0 + wm * 64 + im * 16 + quad * 4;
        int s = mbase >> 2;
#pragma unroll
        for (int in = 0; in < 4; ++in) {
            int e = n0 + wn * 64 + in * 16 + l16;
            int h = e >> 6, dd = e & 63;
            float2 cs = *(const float2*)&FC[s * 64 + (dd & ~1)];
            float sgn = (dd & 1) ? 1.0f : -1.0f;
#pragma unroll
            for (int rr = 0; rr < 4; ++rr) {
                float vv = acc[im][in][rr];
                float pp = __shfl_xor(vv, 1, 64);
                float ov = (vv * cs.x + sgn * pp * cs.y) * osc;
                outb[((size_t)(rr * NHEADS + h) * S_LEN + s) * HDIM + dd] = f2bf(ov);
            }
        }
    }
}

// ---------------------------------------------------------------------------
// V projection GEMM (round-5 structure), transposed-V epilogue with the
// sigma key-permutation. ROUND-8: same A-panel-clustered (m,n) decode.
// ---------------------------------------------------------------------------
__global__ __launch_bounds__(256) void v_gemm(const ushort* __restrict__ vb,
                                              const ushort* __restrict__ wvb,
                                              ushort* __restrict__ Vt) {
    __shared__ __align__(16) ushort A_lds[128 * 32];
    __shared__ __align__(16) ushort B_lds[128 * 32];

    const int tid  = threadIdx.x;
    const int lane = tid & 63;
    const int wvx  = tid >> 6;
    const int wm   = wvx >> 1, wn = wvx & 1;
    const int quad = lane >> 4, l16 = lane & 15;
    const int m0 = (blockIdx.x & 63) * 128;   // A-panel-clustered
    const int n0 = (blockIdx.x >> 6) * 128;

    const int srow = tid >> 2;
    const int scol = (tid & 3) * 8;

    f32x4 acc[4][4] = {};

    for (int k0 = 0; k0 < 1024; k0 += 32) {
        __syncthreads();
        gl16(&vb[(size_t)(m0 + srow) * 1024 + k0 + scol],      &A_lds[tid * 8]);
        gl16(&vb[(size_t)(m0 + 64 + srow) * 1024 + k0 + scol], &A_lds[2048 + tid * 8]);
        gl16(&wvb[(size_t)(n0 + srow) * 1024 + k0 + scol],      &B_lds[tid * 8]);
        gl16(&wvb[(size_t)(n0 + 64 + srow) * 1024 + k0 + scol], &B_lds[2048 + tid * 8]);
        __syncthreads();

        const ushort* Ab = &A_lds[(wm * 64 + l16) * 32 + quad * 8];
        const ushort* Bb = &B_lds[(wn * 64 + l16) * 32 + quad * 8];
        bf16x8 af[4], bfr[4];
#pragma unroll
        for (int i = 0; i < 4; ++i) af[i]  = *(const bf16x8*)(Ab + i * 512);
#pragma unroll
        for (int i = 0; i < 4; ++i) bfr[i] = *(const bf16x8*)(Bb + i * 512);
#pragma unroll
        for (int im = 0; im < 4; ++im)
#pragma unroll
            for (int in = 0; in < 4; ++in)
                acc[im][in] = __builtin_amdgcn_mfma_f32_16x16x32_bf16(
                    af[im], bfr[in], acc[im][in], 0, 0, 0);
    }

#pragma unroll
    for (int im = 0; im < 4; ++im) {
        int mbase = m0 + wm * 64 + im * 16 + quad * 4;
        int s = mbase >> 2;
        int nt2 = (s >> 4) & 3;
        int qd  = (s >> 2) & 3;
        int r2  = s & 3;
        int pos = (s & ~63) | ((nt2 >> 1) << 5) | (qd << 3) | ((nt2 & 1) << 2) | r2;
#pragma unroll
        for (int in = 0; in < 4; ++in) {
            int e = n0 + wn * 64 + in * 16 + l16;
            int h = e >> 6, dd = e & 63;
#pragma unroll
            for (int rr = 0; rr < 4; ++rr) {
                Vt[((size_t)(rr * NHEADS + h) * HDIM + dd) * S_LEN + pos] =
                    f2bf(acc[im][in][rr]);
            }
        }
    }
}

// ---------------------------------------------------------------------------
// Output projection (round-5 structure). ROUND-8: A-panel-clustered decode.
// ---------------------------------------------------------------------------
__global__ __launch_bounds__(256) void out_gemm(const ushort* __restrict__ A,
                                                const ushort* __restrict__ W,
                                                float* __restrict__ outf) {
    __shared__ __align__(16) ushort A_lds[128 * 32];
    __shared__ __align__(16) ushort B_lds[128 * 32];

    const int tid  = threadIdx.x;
    const int lane = tid & 63;
    const int wvx  = tid >> 6;
    const int wm   = wvx >> 1, wn = wvx & 1;
    const int quad = lane >> 4, l16 = lane & 15;
    const int m0 = (blockIdx.x & 63) * 128;   // A-panel-clustered
    const int n0 = (blockIdx.x >> 6) * 128;

    const int srow = tid >> 2;
    const int scol = (tid & 3) * 8;

    f32x4 acc[4][4] = {};

    for (int k0 = 0; k0 < 1024; k0 += 32) {
        __syncthreads();
        gl16(&A[(size_t)(m0 + srow) * 1024 + k0 + scol],      &A_lds[tid * 8]);
        gl16(&A[(size_t)(m0 + 64 + srow) * 1024 + k0 + scol], &A_lds[2048 + tid * 8]);
        gl16(&W[(size_t)(n0 + srow) * 1024 + k0 + scol],      &B_lds[tid * 8]);
        gl16(&W[(size_t)(n0 + 64 + srow) * 1024 + k0 + scol], &B_lds[2048 + tid * 8]);
        __syncthreads();

        const ushort* Ab = &A_lds[(wm * 64 + l16) * 32 + quad * 8];
        const ushort* Bb = &B_lds[(wn * 64 + l16) * 32 + quad * 8];
        bf16x8 af[4], bfr[4];
#pragma unroll
        for (int i = 0; i < 4; ++i) af[i]  = *(const bf16x8*)(Ab + i * 512);
#pragma unroll
        for (int i = 0; i < 4; ++i) bfr[i] = *(const bf16x8*)(Bb + i * 512);
#pragma unroll
        for (int im = 0; im < 4; ++im)
#pragma unroll
            for (int in = 0; in < 4; ++in)
                acc[im][in] = __builtin_amdgcn_mfma_f32_16x16x32_bf16(
                    af[im], bfr[in], acc[im][in], 0, 0, 0);
    }

#pragma unroll
    for (int im = 0; im < 4; ++im) {
        int mbase = m0 + wm * 64 + im * 16 + quad * 4;
#pragma unroll
        for (int in = 0; in < 4; ++in) {
            int e = n0 + wn * 64 + in * 16 + l16;
#pragma unroll
            for (int rr = 0; rr < 4; ++rr)
                outf[(size_t)(mbase + rr) * 1024 + e] = acc[im][in][rr];
        }
    }
}

// ---------------------------------------------------------------------------
// MFMA flash attention — unchanged (round-5 form; ~828 TF, at the plain-HIP
// structure ceiling). Counted-vmcnt dbuf pipeline, in-register softmax via
// swapped operands, sigma-permuted PV, XCD head clustering.
// ---------------------------------------------------------------------------
__global__ __launch_bounds__(256, 4) void attn_mfma(const ushort* __restrict__ Qb,
                                                    const ushort* __restrict__ Kb,
                                                    const ushort* __restrict__ Vt,
                                                    ushort* __restrict__ Ob) {
    __shared__ __align__(16) ushort KV[16384];

    const int tid  = threadIdx.x;
    const int lane = tid & 63;
    const int wv   = tid >> 6;
    const int quad = lane >> 4;
    const int l16  = lane & 15;

    const int bid  = blockIdx.x;
    const int xcd  = bid & 7;
    const int slot = bid >> 3;
    const int head = ((slot >> 4) << 3) | xcd;
    const int qt   = slot & 15;

    const int q0   = qt * 128 + wv * 32;
    const size_t hb = (size_t)head * (S_LEN * HDIM);

    bf16x8 qf[2][2];
#pragma unroll
    for (int im = 0; im < 2; ++im)
#pragma unroll
        for (int kk = 0; kk < 2; ++kk)
            qf[im][kk] = *(const bf16x8*)
                &Qb[hb + (size_t)(q0 + im * 16 + l16) * HDIM + kk * 32 + quad * 8];

    f32x4 o[2][4] = {};
    float lsum[2] = {0.f, 0.f};

    const int srow = tid >> 3;
    const int scol = (((tid & 7) ^ (srow & 7)) * 8);
    const int sx   = (l16 & 7) * 8;

    {
        ushort* dst = &KV[0];
        gl16(&Kb[hb + (size_t)(srow) * HDIM + scol],        dst + tid * 8);
        gl16(&Kb[hb + (size_t)(32 + srow) * HDIM + scol],   dst + 2048 + tid * 8);
        gl16(&Vt[hb + (size_t)srow * S_LEN + scol],         dst + 4096 + tid * 8);
        gl16(&Vt[hb + (size_t)(32 + srow) * S_LEN + scol],  dst + 4096 + 2048 + tid * 8);
    }

#pragma unroll 2
    for (int t = 0; t < 32; ++t) {
        if (t < 31) {
            ushort* dst = &KV[((t + 1) & 1) * 8192];
            const int kc = (t + 1) * 64;
            gl16(&Kb[hb + (size_t)(kc + srow) * HDIM + scol],      dst + tid * 8);
            gl16(&Kb[hb + (size_t)(kc + 32 + srow) * HDIM + scol], dst + 2048 + tid * 8);
            gl16(&Vt[hb + (size_t)srow * S_LEN + kc + scol],       dst + 4096 + tid * 8);
            gl16(&Vt[hb + (size_t)(32 + srow) * S_LEN + kc + scol], dst + 4096 + 2048 + tid * 8);
            asm volatile("s_waitcnt vmcnt(4)" ::: "memory");
        } else {
            asm volatile("s_waitcnt vmcnt(0)" ::: "memory");
        }
        __builtin_amdgcn_s_barrier();
        __builtin_amdgcn_sched_barrier(0);

        const ushort* Ksub = &KV[(t & 1) * 8192];
        const ushort* Vsub = Ksub + 4096;

        f32x4 st[2][4] = {};
        __builtin_amdgcn_s_setprio(1);
#pragma unroll
        for (int nt = 0; nt < 4; ++nt) {
            bf16x8 kf0 = *(const bf16x8*)&Ksub[(nt * 16 + l16) * 64 + ((quad * 8) ^ sx)];
            bf16x8 kf1 = *(const bf16x8*)&Ksub[(nt * 16 + l16) * 64 + ((32 + quad * 8) ^ sx)];
#pragma unroll
            for (int im = 0; im < 2; ++im) {
                st[im][nt] = __builtin_amdgcn_mfma_f32_16x16x32_bf16(
                    kf0, qf[im][0], st[im][nt], 0, 0, 0);
                st[im][nt] = __builtin_amdgcn_mfma_f32_16x16x32_bf16(
                    kf1, qf[im][1], st[im][nt], 0, 0, 0);
            }
        }
        __builtin_amdgcn_s_setprio(0);

        union { uint32 d[16]; bf16x8 v[4]; } P;
#pragma unroll
        for (int im = 0; im < 2; ++im) {
            float ls = 0.f;
#pragma unroll
            for (int nt = 0; nt < 4; ++nt) {
                float p0 = exp2_asm(st[im][nt][0]);
                float p1 = exp2_asm(st[im][nt][1]);
                float p2 = exp2_asm(st[im][nt][2]);
                float p3 = exp2_asm(st[im][nt][3]);
                ls += (p0 + p1) + (p2 + p3);
                P.d[im * 8 + nt * 2]     = pk_bf16(p0, p1);
                P.d[im * 8 + nt * 2 + 1] = pk_bf16(p2, p3);
            }
            lsum[im] += ls;
        }

        __builtin_amdgcn_s_setprio(1);
#pragma unroll
        for (int dt = 0; dt < 4; ++dt) {
            bf16x8 vf0 = *(const bf16x8*)&Vsub[(dt * 16 + l16) * 64 + ((quad * 8) ^ sx)];
            bf16x8 vf1 = *(const bf16x8*)&Vsub[(dt * 16 + l16) * 64 + ((32 + quad * 8) ^ sx)];
#pragma unroll
            for (int im = 0; im < 2; ++im) {
                o[im][dt] = __builtin_amdgcn_mfma_f32_16x16x32_bf16(
                    vf0, P.v[im * 2], o[im][dt], 0, 0, 0);
                o[im][dt] = __builtin_amdgcn_mfma_f32_16x16x32_bf16(
                    vf1, P.v[im * 2 + 1], o[im][dt], 0, 0, 0);
            }
        }
        __builtin_amdgcn_s_setprio(0);

        __builtin_amdgcn_s_barrier();
        __builtin_amdgcn_sched_barrier(0);
    }

#pragma unroll
    for (int im = 0; im < 2; ++im) {
        lsum[im] += __shfl_xor(lsum[im], 16, 64);
        lsum[im] += __shfl_xor(lsum[im], 32, 64);
    }

    ushort* Est = &KV[wv * 2048];
#pragma unroll
    for (int im = 0; im < 2; ++im) {
        float inv = 1.0f / lsum[im];
#pragma unroll
        for (int dt = 0; dt < 4; ++dt) {
            uint2 w;
            w.x = pk_bf16(o[im][dt][0] * inv, o[im][dt][1] * inv);
            w.y = pk_bf16(o[im][dt][2] * inv, o[im][dt][3] * inv);
            *(uint2*)&Est[(im * 16 + l16) * 64 + dt * 16 + quad * 4] = w;
        }
    }
    __syncthreads();

    const int row  = lane >> 1, half = lane & 1;
    const int b = head >> 4, h = head & 15;
    const size_t ob = (size_t)((q0 + row) * BATCH + b) * 1024 + h * 64 + half * 32;
#pragma unroll
    for (int e = 0; e < 4; ++e) {
        bf16x8 t = *(const bf16x8*)&Est[row * 64 + half * 32 + e * 8];
        *(bf16x8*)&Ob[ob + e * 8] = t;
    }
}

extern "C" void kernel_launch(void* const* d_in, const int* in_sizes, int n_in,
                              void* d_out, int out_size, void* d_ws, size_t ws_size,
                              hipStream_t stream) {
    const float* q   = (const float*)d_in[0];
    const float* k   = (const float*)d_in[1];
    const float* v   = (const float*)d_in[2];
    const float* fc  = (const float*)d_in[3];
    const float* wq  = (const float*)d_in[4];
    const float* wk  = (const float*)d_in[5];
    const float* wvp = (const float*)d_in[6];
    const float* wo  = (const float*)d_in[7];

    ushort* ws = (ushort*)d_ws;
    // ws layout (56 MB): qb | kb | vb | wqb wkb wvb wob
    // Vt reuses qb (dead after qk_gemm launch); R3 reuses kb.
    ushort* qb  = ws;
    ushort* kb  = ws + NE_;
    ushort* vb  = ws + 2 * (size_t)NE_;
    ushort* wqb = ws + 3 * (size_t)NE_;
    ushort* wkb = wqb + WE_;
    ushort* wvb = wqb + 2 * (size_t)WE_;
    ushort* wob = wqb + 3 * (size_t)WE_;

    ushort* Qh = (ushort*)d_out;
    ushort* Kh = Qh + NE_;
    ushort* Vt = ws;            // qb region
    ushort* R3 = ws + NE_;      // kb region

    // 1. convert everything to bf16
    cvt_all<<<28672, 256, 0, stream>>>(q, k, v, wq, wk, wvp, wo, ws);

    // 2. fused Q+K projection + RoPE -> d_out scratch
    qk_gemm<<<1024, 256, 0, stream>>>(qb, kb, wqb, wkb, fc, Qh, Kh);

    // 3. V projection (transposed + sigma key axis) -> qb region
    v_gemm<<<512, 256, 0, stream>>>(vb, wvb, Vt);

    // 4. MFMA flash attention -> kb region
    attn_mfma<<<1024, 256, 0, stream>>>(Qh, Kh, Vt, R3);

    // 5. output projection -> d_out fp32
    out_gemm<<<512, 256, 0, stream>>>(R3, wob, (float*)d_out);
}